// Round 17
// baseline (566.840 us; speedup 1.0000x reference)
//
#include <hip/hip_runtime.h>
#include <hip/hip_bf16.h>
#include <stdint.h>

typedef unsigned short u16;
typedef __attribute__((ext_vector_type(8))) short bf16x8;
typedef __attribute__((ext_vector_type(4))) float f32x4;

#define LDS_AS __attribute__((address_space(3)))
#define GLB_AS __attribute__((address_space(1)))

// T=1024, B=8, E=1024, H=16, hd=64, N=B*H=128, M=T*B=8192

__device__ __forceinline__ u16 f2bf(float f) {
  union { float f; uint32_t u; } v; v.f = f;
  uint32_t u = v.u;
  u += 0x7FFFu + ((u >> 16) & 1u);   // RNE
  return (u16)(u >> 16);
}

__device__ __forceinline__ f32x4 mfma16(bf16x8 a, bf16x8 b, f32x4 c) {
  return __builtin_amdgcn_mfma_f32_16x16x32_bf16(a, b, c, 0, 0, 0);
}

__device__ __forceinline__ void gll16(const void* g, void* l) {
  __builtin_amdgcn_global_load_lds((const GLB_AS void*)(uintptr_t)g,
                                   (LDS_AS void*)(uintptr_t)l, 16, 0, 0);
}

// ---------------- fp32 -> bf16 convert, single launch for all 7 tensors ----------------
__global__ __launch_bounds__(256) void k_cvt_all(
    const float* __restrict__ a0, const float* __restrict__ a1, const float* __restrict__ a2,
    const float* __restrict__ w0, const float* __restrict__ w1,
    const float* __restrict__ w2, const float* __restrict__ w3,
    u16* __restrict__ da0, u16* __restrict__ da1, u16* __restrict__ da2,
    u16* __restrict__ dw0, u16* __restrict__ dw1, u16* __restrict__ dw2, u16* __restrict__ dw3)
{
  int gid = blockIdx.x;
  const float* s; u16* d; int idx;
  if (gid < 24576) {
    int seg = gid >> 13; idx = gid & 8191;
    s = seg == 0 ? a0 : (seg == 1 ? a1 : a2);
    d = seg == 0 ? da0 : (seg == 1 ? da1 : da2);
  } else {
    int g2 = gid - 24576;
    int seg = g2 >> 10; idx = g2 & 1023;
    s = seg == 0 ? w0 : (seg == 1 ? w1 : (seg == 2 ? w2 : w3));
    d = seg == 0 ? dw0 : (seg == 1 ? dw1 : (seg == 2 ? dw2 : dw3));
  }
  int i = (idx * 256 + threadIdx.x) * 4;
  float4 v = *reinterpret_cast<const float4*>(s + i);
  ushort4 o;
  o.x = f2bf(v.x); o.y = f2bf(v.y); o.z = f2bf(v.z); o.w = f2bf(v.w);
  *reinterpret_cast<ushort4*>(d + i) = o;
}

// ---------------- GEMM core ----------------
// mode 0: *0.125 bf16 -> [n][t][d] (q) ; mode 1: bf16 -> [n][t][d] (k)
// mode 2: bf16 -> vt[n][d][t] (v, fused transpose) ; mode 3: fp32 -> [i][j]
__device__ __forceinline__ void gemm_core(
    const u16* __restrict__ A, const u16* __restrict__ Bw,
    const float* __restrict__ bias, void* __restrict__ outp, int mode)
{
  __shared__ u16 smem[2 * 128 * 64];   // staging A/B; epilogue: 128x128 bf16 tile
  u16* aLds = smem;
  u16* bLds = smem + 128 * 64;
  const int tid = threadIdx.x;
  const int w = tid >> 6, lane = tid & 63;
  const int fr = lane & 15, fh = lane >> 4;
  const int m0 = blockIdx.x * 128, n0 = blockIdx.y * 128;
  const int wr = w >> 1, wc = w & 1;
  const int srow = tid >> 3, scol = (tid & 7) * 8;

  f32x4 zero4 = {0.f, 0.f, 0.f, 0.f};
  f32x4 acc[4][4];
#pragma unroll
  for (int i = 0; i < 4; i++)
#pragma unroll
    for (int j = 0; j < 4; j++) acc[i][j] = zero4;

  const u16* ag = A + (size_t)(m0 + srow) * 1024 + scol;
  const u16* bg = Bw + (size_t)(n0 + srow) * 1024 + scol;

  for (int k0 = 0; k0 < 1024; k0 += 64) {
#pragma unroll
    for (int it = 0; it < 4; ++it) {
      gll16(ag + (size_t)it * 32 * 1024 + k0, aLds + it * 2048 + w * 512);
      gll16(bg + (size_t)it * 32 * 1024 + k0, bLds + it * 2048 + w * 512);
    }
    __syncthreads();
#pragma unroll
    for (int ks = 0; ks < 2; ++ks) {
      bf16x8 af[4], bfr[4];
#pragma unroll
      for (int mi = 0; mi < 4; mi++)
        af[mi] = *reinterpret_cast<const bf16x8*>(&aLds[(wr * 64 + mi * 16 + fr) * 64 + ks * 32 + fh * 8]);
#pragma unroll
      for (int nj = 0; nj < 4; nj++)
        bfr[nj] = *reinterpret_cast<const bf16x8*>(&bLds[(wc * 64 + nj * 16 + fr) * 64 + ks * 32 + fh * 8]);
#pragma unroll
      for (int mi = 0; mi < 4; mi++)
#pragma unroll
        for (int nj = 0; nj < 4; nj++)
          acc[mi][nj] = mfma16(af[mi], bfr[nj], acc[mi][nj]);
    }
    __syncthreads();
  }

  if (mode == 3) {
#pragma unroll
    for (int nj = 0; nj < 4; nj++) {
      int j = n0 + wc * 64 + nj * 16 + fr;
      float bj = bias[j];
#pragma unroll
      for (int mi = 0; mi < 4; mi++) {
#pragma unroll
        for (int r = 0; r < 4; r++) {
          int i = m0 + wr * 64 + mi * 16 + fh * 4 + r;
          ((float*)outp)[(size_t)i * 1024 + j] = acc[mi][nj][r] + bj;
        }
      }
    }
    return;
  }

  // stage bf16 result into 128x128 LDS tile, XOR-swizzled (j ^= (i&7)<<3)
  float scale = (mode == 0) ? 0.125f : 1.0f;
#pragma unroll
  for (int nj = 0; nj < 4; nj++) {
    int j = wc * 64 + nj * 16 + fr;
    float bj = bias[n0 + j];
#pragma unroll
    for (int mi = 0; mi < 4; mi++) {
#pragma unroll
      for (int r = 0; r < 4; r++) {
        int i = wr * 64 + mi * 16 + fh * 4 + r;
        smem[i * 128 + (j ^ ((i & 7) << 3))] = f2bf((acc[mi][nj][r] + bj) * scale);
      }
    }
  }
  __syncthreads();

  if (mode == 2) {
    // fused transpose: vt[n][d][t], t-run of 16 per (b,h,d) -> 2 dwordx4
    int t0 = m0 >> 3;
#pragma unroll
    for (int rr2 = 0; rr2 < 4; ++rr2) {
      int rid = rr2 * 256 + tid;           // 0..1023
      int b = rid & 7, jh = (rid >> 3) & 1, d = rid >> 4;
      int j_loc = jh * 64 + d;
      u16 tmp[16];
#pragma unroll
      for (int tt = 0; tt < 16; ++tt) {
        int i_loc = tt * 8 + b;
        tmp[tt] = smem[i_loc * 128 + (j_loc ^ ((i_loc & 7) << 3))];
      }
      int n = b * 16 + ((n0 + j_loc) >> 6);
      int d_ = (n0 + j_loc) & 63;
      u16* dst = (u16*)outp + (size_t)n * 65536 + (size_t)d_ * 1024 + t0;
      *reinterpret_cast<uint4*>(dst)     = *reinterpret_cast<const uint4*>(&tmp[0]);
      *reinterpret_cast<uint4*>(dst + 8) = *reinterpret_cast<const uint4*>(&tmp[8]);
    }
  } else {
    // coalesced [n][t][d] store: 2048 chunks of 8 bf16 (128B runs)
#pragma unroll
    for (int it = 0; it < 8; ++it) {
      int g = w * 512 + it * 64 + lane;
      int i = g >> 4;
      int cg = (g & 15) * 8;
      uint4 v = *reinterpret_cast<const uint4*>(&smem[i * 128 + (cg ^ ((i & 7) << 3))]);
      int t = (m0 + i) >> 3, b = i & 7;
      int jg = n0 + cg;
      int h = jg >> 6, d = jg & 63;
      *reinterpret_cast<uint4*>(&((u16*)outp)[((size_t)((b * 16 + h) * 1024 + t)) * 64 + d]) = v;
    }
  }
}

__global__ __launch_bounds__(256) void k_gemm_qkv(
    const u16* __restrict__ xq, const u16* __restrict__ xk, const u16* __restrict__ xv,
    const u16* __restrict__ wq, const u16* __restrict__ wk, const u16* __restrict__ wv,
    const float* __restrict__ bq, const float* __restrict__ bk, const float* __restrict__ bv,
    u16* __restrict__ qo, u16* __restrict__ ko, u16* __restrict__ vto)
{
  int z = blockIdx.z;
  const u16* A = z == 0 ? xq : (z == 1 ? xk : xv);
  const u16* Bw = z == 0 ? wq : (z == 1 ? wk : wv);
  const float* bias = z == 0 ? bq : (z == 1 ? bk : bv);
  u16* o = z == 0 ? qo : (z == 1 ? ko : vto);
  gemm_core(A, Bw, bias, o, z);   // 0=q, 1=k, 2=v->vt
}

__global__ __launch_bounds__(256) void k_gemm_o(
    const u16* __restrict__ A, const u16* __restrict__ Bw,
    const float* __restrict__ bias, float* __restrict__ outp)
{
  gemm_core(A, Bw, bias, outp, 3);
}

// ---------------- flash attention step: one 64-s block for one t-block ----------------
__device__ __forceinline__ void attn_step(
    const u16* lds_k, u16* lds_p, const bf16x8 (&vf)[2][4],
    int sb, int tb_, int w, int fr, int fh,
    bf16x8 qf0, bf16x8 qf1,
    f32x4 (&oacc)[4], float (&m4)[4], float (&l4)[4])
{
  int t0 = tb_ * 64 + w * 16;
  f32x4 dd[4];
#pragma unroll
  for (int ss = 0; ss < 4; ++ss) {
    int row = ss * 16 + fr;
    const u16* kr = lds_k + row * 64;
    int c0 = (fh * 16) ^ ((row & 7) << 4);
    int c1 = (64 + fh * 16) ^ ((row & 7) << 4);
    bf16x8 kf0 = *reinterpret_cast<const bf16x8*>(kr + (c0 >> 1));
    bf16x8 kf1 = *reinterpret_cast<const bf16x8*>(kr + (c1 >> 1));
    f32x4 z = {0.f, 0.f, 0.f, 0.f};
    z = mfma16(qf0, kf0, z);
    dd[ss] = mfma16(qf1, kf1, z);
  }
  if (sb == tb_) {   // diagonal block: causal mask
#pragma unroll
    for (int ss = 0; ss < 4; ++ss) {
      int s_c = sb * 64 + ss * 16 + fr;
#pragma unroll
      for (int r = 0; r < 4; ++r)
        if (s_c > t0 + fh * 4 + r) dd[ss][r] = -3.0e38f;
    }
  }
  float mn[4], scale[4];
#pragma unroll
  for (int r = 0; r < 4; ++r) {
    float bm = fmaxf(fmaxf(dd[0][r], dd[1][r]), fmaxf(dd[2][r], dd[3][r]));
#pragma unroll
    for (int bmk = 1; bmk < 16; bmk <<= 1)
      bm = fmaxf(bm, __shfl_xor(bm, bmk, 64));
    mn[r] = fmaxf(m4[r], bm);
    scale[r] = __expf(m4[r] - mn[r]);
    m4[r] = mn[r];
  }
#pragma unroll
  for (int ss = 0; ss < 4; ++ss) {
#pragma unroll
    for (int r = 0; r < 4; ++r) {
      float p = __expf(dd[ss][r] - mn[r]);
      dd[ss][r] = p;
      int row = fh * 4 + r;
      int cb = ((ss * 16 + fr) * 2) ^ ((row & 7) << 4);
      lds_p[row * 64 + (cb >> 1)] = f2bf(p);
    }
  }
#pragma unroll
  for (int r = 0; r < 4; ++r) {
    float s = (dd[0][r] + dd[1][r]) + (dd[2][r] + dd[3][r]);
#pragma unroll
    for (int bmk = 1; bmk < 16; bmk <<= 1)
      s += __shfl_xor(s, bmk, 64);
    l4[r] = l4[r] * scale[r] + s;
#pragma unroll
    for (int db = 0; db < 4; ++db) oacc[db][r] *= scale[r];
  }
  asm volatile("s_waitcnt lgkmcnt(0)" ::: "memory");
  __builtin_amdgcn_sched_barrier(0);
#pragma unroll
  for (int ks = 0; ks < 2; ++ks) {
    int pc = (ks * 64 + fh * 16) ^ ((fr & 7) << 4);
    bf16x8 pa = *reinterpret_cast<const bf16x8*>(lds_p + fr * 64 + (pc >> 1));
#pragma unroll
    for (int db = 0; db < 4; ++db)
      oacc[db] = mfma16(pa, vf[ks][db], oacc[db]);
  }
}

// ---------------- attention: grid (n=128, j=8); block does t-blocks {15-j, j} ----------------
__global__ __launch_bounds__(256) void k_attn(
    const u16* __restrict__ qb, const u16* __restrict__ kb, const u16* __restrict__ vt,
    float* __restrict__ m_ws, float* __restrict__ l_ws, u16* __restrict__ attn_pre)
{
  __shared__ u16 kT[2][64 * 64];
  __shared__ u16 pT[4][16 * 64];
  int tid = threadIdx.x, w = tid >> 6, lane = tid & 63;
  int fr = lane & 15, fh = lane >> 4;
  int n = blockIdx.x, j = blockIdx.y;
  int tbH = 15 - j, tbL = j;
  const u16* kb_n = kb + (size_t)n * 1024 * 64;
  const u16* vt_n = vt + (size_t)n * 64 * 1024;

  bf16x8 qfH0, qfH1, qfL0, qfL1;
  {
    const u16* q = qb + ((size_t)n * 1024 + tbH * 64 + w * 16 + fr) * 64;
    qfH0 = *reinterpret_cast<const bf16x8*>(q + fh * 8);
    qfH1 = *reinterpret_cast<const bf16x8*>(q + 32 + fh * 8);
    q = qb + ((size_t)n * 1024 + tbL * 64 + w * 16 + fr) * 64;
    qfL0 = *reinterpret_cast<const bf16x8*>(q + fh * 8);
    qfL1 = *reinterpret_cast<const bf16x8*>(q + 32 + fh * 8);
  }
  f32x4 oaccH[4], oaccL[4];
  float mH[4], lH[4], mL[4], lL[4];
#pragma unroll
  for (int i = 0; i < 4; ++i) {
    oaccH[i] = (f32x4){0.f, 0.f, 0.f, 0.f};
    oaccL[i] = (f32x4){0.f, 0.f, 0.f, 0.f};
    mH[i] = -3.0e38f; lH[i] = 0.f; mL[i] = -3.0e38f; lL[i] = 0.f;
  }

  auto stage = [&](int buf, int sb) {
#pragma unroll
    for (int it = 0; it < 2; ++it) {
      int rbase = w * 16 + it * 8;
      int row = rbase + (lane >> 3);
      int colb = ((lane & 7) * 16) ^ ((lane >> 3) << 4);
      const u16* src = kb_n + ((size_t)(sb * 64 + row)) * 64 + (colb >> 1);
      gll16(src, &kT[buf][rbase * 64]);
    }
  };

  stage(0, 0);
  asm volatile("s_waitcnt vmcnt(0)" ::: "memory");
  __syncthreads();
  int cur = 0;
  for (int sb = 0; sb <= tbH; ++sb) {
    if (sb < tbH) stage(cur ^ 1, sb + 1);
    bf16x8 vf[2][4];
#pragma unroll
    for (int ks = 0; ks < 2; ++ks)
#pragma unroll
      for (int db = 0; db < 4; ++db)
        vf[ks][db] = *reinterpret_cast<const bf16x8*>(
            vt_n + ((size_t)(db * 16 + fr)) * 1024 + sb * 64 + ks * 32 + fh * 8);
    attn_step(kT[cur], pT[w], vf, sb, tbH, w, fr, fh, qfH0, qfH1, oaccH, mH, lH);
    if (sb <= tbL)
      attn_step(kT[cur], pT[w], vf, sb, tbL, w, fr, fh, qfL0, qfL1, oaccL, mL, lL);
    asm volatile("s_waitcnt vmcnt(0)" ::: "memory");
    __syncthreads();
    cur ^= 1;
  }

  int b_ = n >> 4, h_ = n & 15;
  {
    int t0 = tbH * 64 + w * 16;
    if (fr == 0) {
#pragma unroll
      for (int r = 0; r < 4; ++r) {
        m_ws[n * 1024 + t0 + fh * 4 + r] = mH[r];
        l_ws[n * 1024 + t0 + fh * 4 + r] = lH[r];
      }
    }
#pragma unroll
    for (int db = 0; db < 4; ++db)
#pragma unroll
      for (int r = 0; r < 4; ++r)
        attn_pre[((size_t)((t0 + fh * 4 + r) * 8 + b_)) * 1024 + h_ * 64 + db * 16 + fr] =
            f2bf(oaccH[db][r] / lH[r]);
  }
  {
    int t0 = tbL * 64 + w * 16;
    if (fr == 0) {
#pragma unroll
      for (int r = 0; r < 4; ++r) {
        m_ws[n * 1024 + t0 + fh * 4 + r] = mL[r];
        l_ws[n * 1024 + t0 + fh * 4 + r] = lL[r];
      }
    }
#pragma unroll
    for (int db = 0; db < 4; ++db)
#pragma unroll
      for (int r = 0; r < 4; ++r)
        attn_pre[((size_t)((t0 + fh * 4 + r) * 8 + b_)) * 1024 + h_ * 64 + db * 16 + fr] =
            f2bf(oaccL[db][r] / lL[r]);
  }
}

// ---------------- weights + avg: single 64KB buffer, 2 blocks/CU ----------------
// r13 chunk structure (32 chunks = (h, K-half), 512 K-rows each) but ONE 64 KB buffer:
// per chunk: barrierA -> stage(cc) -> vmcnt(0) -> barrierB -> compute+store.
// Serial within a block; __launch_bounds__(512,4) => 2 blocks/CU so the co-resident
// block's compute/stores cover this block's stage/drain stalls (r12 showed the cost is
// fixed pipeline overhead at 1 blk/CU, not compute/stores).
__global__ __launch_bounds__(512, 4) void k_weights(
    const u16* __restrict__ qb, const u16* __restrict__ kb,
    const float* __restrict__ m_ws, const float* __restrict__ l_ws,
    float* __restrict__ wout, float* __restrict__ avg)
{
  __shared__ u16 kT[512 * 64];   // 64 KB, swizzled
  const float L2E = 1.4426950408889634f;
  int pid = blockIdx.x;
  int b = pid >> 5, pr = pid & 31;
  int tid = threadIdx.x;
  int w = tid >> 6, lane = tid & 63, fr = lane & 15, fh = lane >> 4;
  f32x4 zero4 = {0.f, 0.f, 0.f, 0.f};

  int pA = pr, pB = 63 - pr;       // pA < 32 <= pB
  int t0A = pA * 16, t0B = pB * 16;

  f32x4 avgA[8], avgB[8];
#pragma unroll
  for (int i = 0; i < 8; ++i) { avgA[i] = zero4; avgB[i] = zero4; }

  const int srow8 = lane >> 3;                        // 0..7
  const int scolb = ((lane & 7) * 16) ^ (srow8 << 4); // pre-swizzled byte col

  auto stage = [&](int cc) {
    const u16* kb_n = kb + (size_t)(b * 16 + (cc >> 1)) * 65536;
    int base = (cc & 1) * 512;
#pragma unroll
    for (int j = 0; j < 8; ++j) {
      int rbase = j * 64 + w * 8;
      const u16* src = kb_n + ((size_t)(base + rbase + srow8)) * 64 + (scolb >> 1);
      gll16(src, &kT[rbase * 64]);
    }
  };

  bf16x8 qA0, qA1, qB0, qB1;
  float cA = 0.f, cB = 0.f;
  float* wrowA = nullptr;
  float* wrowB = nullptr;

  for (int h = 0; h < 16; ++h) {
    int n = b * 16 + h;
#pragma unroll
    for (int kh = 0; kh < 2; ++kh) {
      int cc = h * 2 + kh;
      __builtin_amdgcn_s_barrier();                 // A: all waves done reading kT
      __builtin_amdgcn_sched_barrier(0);
      stage(cc);
      __builtin_amdgcn_sched_barrier(0);
      asm volatile("s_waitcnt vmcnt(0)" ::: "memory");  // stage done (stores drain too;
                                                         // covered by co-resident block)
      __builtin_amdgcn_s_barrier();                 // B: staged data visible
      __builtin_amdgcn_sched_barrier(0);

      if (kh == 0) {
        const u16* qrA = qb + ((size_t)n * 1024 + t0A + fr) * 64;
        const u16* qrB = qb + ((size_t)n * 1024 + t0B + fr) * 64;
        qA0 = *reinterpret_cast<const bf16x8*>(qrA + fh * 8);
        qA1 = *reinterpret_cast<const bf16x8*>(qrA + 32 + fh * 8);
        qB0 = *reinterpret_cast<const bf16x8*>(qrB + fh * 8);
        qB1 = *reinterpret_cast<const bf16x8*>(qrB + 32 + fh * 8);
        cA = -m_ws[n * 1024 + t0A + fr] * L2E - __log2f(l_ws[n * 1024 + t0A + fr]);
        cB = -m_ws[n * 1024 + t0B + fr] * L2E - __log2f(l_ws[n * 1024 + t0B + fr]);
        wrowA = wout + ((size_t)n << 20) + ((size_t)t0A << 10);
        wrowB = wout + ((size_t)n << 20) + ((size_t)t0B << 10);
      }

#pragma unroll
      for (int i = 0; i < 4; ++i) {
        int sl = w + 8 * i;                          // chunk-local s-block 0..31
        int sg = kh * 32 + sl;                       // global s-block 0..63
        f32x4 wvA = zero4, wvB = zero4;
        if (sg <= pB) {                              // wave-uniform
          int rowl = sl * 16 + fr;
          const u16* kr = &kT[rowl * 64];
          int c0 = (fh * 16) ^ ((rowl & 7) << 4);
          int c1 = (64 + fh * 16) ^ ((rowl & 7) << 4);
          bf16x8 kf0 = *reinterpret_cast<const bf16x8*>(kr + (c0 >> 1));
          bf16x8 kf1 = *reinterpret_cast<const bf16x8*>(kr + (c1 >> 1));
          if (sg <= pA) {                            // half A valid
            f32x4 dd = zero4;
            dd = mfma16(kf0, qA0, dd);
            dd = mfma16(kf1, qA1, dd);
#pragma unroll
            for (int rr = 0; rr < 4; ++rr) {
              bool valid = (sg < pA) | (fh * 4 + rr <= fr);
              wvA[rr] = valid ? __builtin_amdgcn_exp2f(dd[rr] * L2E + cA) : 0.f;
            }
          }
          {                                          // half B valid (sg <= pB)
            f32x4 dd = zero4;
            dd = mfma16(kf0, qB0, dd);
            dd = mfma16(kf1, qB1, dd);
#pragma unroll
            for (int rr = 0; rr < 4; ++rr) {
              bool valid = (sg < pB) | (fh * 4 + rr <= fr);
              wvB[rr] = valid ? __builtin_amdgcn_exp2f(dd[rr] * L2E + cB) : 0.f;
            }
          }
        }
        avgA[kh * 4 + i] += wvA;
        avgB[kh * 4 + i] += wvB;
        *reinterpret_cast<f32x4*>(wrowA + (size_t)fr * 1024 + sg * 16 + fh * 4) = wvA;
        *reinterpret_cast<f32x4*>(wrowB + (size_t)fr * 1024 + sg * 16 + fh * 4) = wvB;
      }
    }
  }

  // avg: rows t0..t0+15 for both panels; ALL s-slots written (invalid = zero regs)
  float* arowA = avg + (((size_t)b << 10) + t0A) * 1024;
  float* arowB = avg + (((size_t)b << 10) + t0B) * 1024;
#pragma unroll
  for (int i = 0; i < 8; ++i) {
    int sg = (i >> 2) * 32 + (w + 8 * (i & 3));
    f32x4 vA = avgA[i], vB = avgB[i];
#pragma unroll
    for (int rr = 0; rr < 4; ++rr) { vA[rr] *= 0.0625f; vB[rr] *= 0.0625f; }
    *reinterpret_cast<f32x4*>(arowA + (size_t)fr * 1024 + sg * 16 + fh * 4) = vA;
    *reinterpret_cast<f32x4*>(arowB + (size_t)fr * 1024 + sg * 16 + fh * 4) = vB;
  }
}

// ---------------- launcher ----------------
extern "C" void kernel_launch(void* const* d_in, const int* in_sizes, int n_in,
                              void* d_out, int out_size, void* d_ws, size_t ws_size,
                              hipStream_t stream)
{
  const float* query = (const float*)d_in[0];
  const float* key_  = (const float*)d_in[1];
  const float* value = (const float*)d_in[2];
  const float* Wq = (const float*)d_in[5];
  const float* bq = (const float*)d_in[6];
  const float* Wk = (const float*)d_in[7];
  const float* bk = (const float*)d_in[8];
  const float* Wv = (const float*)d_in[9];
  const float* bv = (const float*)d_in[10];
  const float* Wo = (const float*)d_in[11];
  const float* bo = (const float*)d_in[12];

  char* ws = (char*)d_ws;
  size_t off = 0;
  auto alloc = [&](size_t bytes) { char* p = ws + off; off += (bytes + 255) & ~255ull; return p; };

  u16* xq   = (u16*)alloc(8192ull * 1024 * 2);
  u16* xk   = (u16*)alloc(8192ull * 1024 * 2);
  u16* xv   = (u16*)alloc(8192ull * 1024 * 2);
  u16* wqb  = (u16*)alloc(1024ull * 1024 * 2);
  u16* wkb  = (u16*)alloc(1024ull * 1024 * 2);
  u16* wvb  = (u16*)alloc(1024ull * 1024 * 2);
  u16* wob  = (u16*)alloc(1024ull * 1024 * 2);
  u16* qbuf = (u16*)alloc(128ull * 1024 * 64 * 2);
  u16* kbuf = (u16*)alloc(128ull * 1024 * 64 * 2);
  u16* vtb  = (u16*)alloc(128ull * 64 * 1024 * 2);
  u16* apre = (u16*)alloc(8192ull * 1024 * 2);
  float* mws = (float*)alloc(128ull * 1024 * 4);
  float* lws = (float*)alloc(128ull * 1024 * 4);

  float* out_attn = (float*)d_out;                  // [1024,8,1024]
  float* out_avg  = out_attn + 8388608;             // [8,1024,1024]
  float* out_w    = out_avg + 8388608;              // [8,16,1024,1024]

  k_cvt_all<<<28672, 256, 0, stream>>>(query, key_, value, Wq, Wk, Wv, Wo,
                                       xq, xk, xv, wqb, wkb, wvb, wob);

  k_gemm_qkv<<<dim3(64, 8, 3), 256, 0, stream>>>(xq, xk, xv, wqb, wkb, wvb,
                                                 bq, bk, bv, qbuf, kbuf, vtb);

  k_attn<<<dim3(128, 8), 256, 0, stream>>>(qbuf, kbuf, vtb, mws, lws, apre);
  k_weights<<<256, 512, 0, stream>>>(qbuf, kbuf, mws, lws, out_w, out_avg);
  k_gemm_o<<<dim3(64, 8), 256, 0, stream>>>(apre, wob, bo, out_attn);
}

// Round 18
// 381.135 us; speedup vs baseline: 1.4872x; 1.4872x over previous
//
#include <hip/hip_runtime.h>
#include <hip/hip_bf16.h>
#include <stdint.h>

typedef unsigned short u16;
typedef __attribute__((ext_vector_type(8))) short bf16x8;
typedef __attribute__((ext_vector_type(4))) float f32x4;

#define LDS_AS __attribute__((address_space(3)))
#define GLB_AS __attribute__((address_space(1)))

// T=1024, B=8, E=1024, H=16, hd=64, N=B*H=128, M=T*B=8192

__device__ __forceinline__ u16 f2bf(float f) {
  union { float f; uint32_t u; } v; v.f = f;
  uint32_t u = v.u;
  u += 0x7FFFu + ((u >> 16) & 1u);   // RNE
  return (u16)(u >> 16);
}

__device__ __forceinline__ f32x4 mfma16(bf16x8 a, bf16x8 b, f32x4 c) {
  return __builtin_amdgcn_mfma_f32_16x16x32_bf16(a, b, c, 0, 0, 0);
}

__device__ __forceinline__ void gll16(const void* g, void* l) {
  __builtin_amdgcn_global_load_lds((const GLB_AS void*)(uintptr_t)g,
                                   (LDS_AS void*)(uintptr_t)l, 16, 0, 0);
}

// ---------------- fp32 -> bf16 convert, single launch for all 7 tensors ----------------
__global__ __launch_bounds__(256) void k_cvt_all(
    const float* __restrict__ a0, const float* __restrict__ a1, const float* __restrict__ a2,
    const float* __restrict__ w0, const float* __restrict__ w1,
    const float* __restrict__ w2, const float* __restrict__ w3,
    u16* __restrict__ da0, u16* __restrict__ da1, u16* __restrict__ da2,
    u16* __restrict__ dw0, u16* __restrict__ dw1, u16* __restrict__ dw2, u16* __restrict__ dw3)
{
  int gid = blockIdx.x;
  const float* s; u16* d; int idx;
  if (gid < 24576) {
    int seg = gid >> 13; idx = gid & 8191;
    s = seg == 0 ? a0 : (seg == 1 ? a1 : a2);
    d = seg == 0 ? da0 : (seg == 1 ? da1 : da2);
  } else {
    int g2 = gid - 24576;
    int seg = g2 >> 10; idx = g2 & 1023;
    s = seg == 0 ? w0 : (seg == 1 ? w1 : (seg == 2 ? w2 : w3));
    d = seg == 0 ? dw0 : (seg == 1 ? dw1 : (seg == 2 ? dw2 : dw3));
  }
  int i = (idx * 256 + threadIdx.x) * 4;
  float4 v = *reinterpret_cast<const float4*>(s + i);
  ushort4 o;
  o.x = f2bf(v.x); o.y = f2bf(v.y); o.z = f2bf(v.z); o.w = f2bf(v.w);
  *reinterpret_cast<ushort4*>(d + i) = o;
}

// ---------------- GEMM core ----------------
// mode 0: *0.125 bf16 -> [n][t][d] (q) ; mode 1: bf16 -> [n][t][d] (k)
// mode 2: bf16 -> vt[n][d][t] (v, fused transpose) ; mode 3: fp32 -> [i][j]
__device__ __forceinline__ void gemm_core(
    const u16* __restrict__ A, const u16* __restrict__ Bw,
    const float* __restrict__ bias, void* __restrict__ outp, int mode)
{
  __shared__ u16 smem[2 * 128 * 64];   // staging A/B; epilogue: 128x128 bf16 tile
  u16* aLds = smem;
  u16* bLds = smem + 128 * 64;
  const int tid = threadIdx.x;
  const int w = tid >> 6, lane = tid & 63;
  const int fr = lane & 15, fh = lane >> 4;
  const int m0 = blockIdx.x * 128, n0 = blockIdx.y * 128;
  const int wr = w >> 1, wc = w & 1;
  const int srow = tid >> 3, scol = (tid & 7) * 8;

  f32x4 zero4 = {0.f, 0.f, 0.f, 0.f};
  f32x4 acc[4][4];
#pragma unroll
  for (int i = 0; i < 4; i++)
#pragma unroll
    for (int j = 0; j < 4; j++) acc[i][j] = zero4;

  const u16* ag = A + (size_t)(m0 + srow) * 1024 + scol;
  const u16* bg = Bw + (size_t)(n0 + srow) * 1024 + scol;

  for (int k0 = 0; k0 < 1024; k0 += 64) {
#pragma unroll
    for (int it = 0; it < 4; ++it) {
      gll16(ag + (size_t)it * 32 * 1024 + k0, aLds + it * 2048 + w * 512);
      gll16(bg + (size_t)it * 32 * 1024 + k0, bLds + it * 2048 + w * 512);
    }
    __syncthreads();
#pragma unroll
    for (int ks = 0; ks < 2; ++ks) {
      bf16x8 af[4], bfr[4];
#pragma unroll
      for (int mi = 0; mi < 4; mi++)
        af[mi] = *reinterpret_cast<const bf16x8*>(&aLds[(wr * 64 + mi * 16 + fr) * 64 + ks * 32 + fh * 8]);
#pragma unroll
      for (int nj = 0; nj < 4; nj++)
        bfr[nj] = *reinterpret_cast<const bf16x8*>(&bLds[(wc * 64 + nj * 16 + fr) * 64 + ks * 32 + fh * 8]);
#pragma unroll
      for (int mi = 0; mi < 4; mi++)
#pragma unroll
        for (int nj = 0; nj < 4; nj++)
          acc[mi][nj] = mfma16(af[mi], bfr[nj], acc[mi][nj]);
    }
    __syncthreads();
  }

  if (mode == 3) {
#pragma unroll
    for (int nj = 0; nj < 4; nj++) {
      int j = n0 + wc * 64 + nj * 16 + fr;
      float bj = bias[j];
#pragma unroll
      for (int mi = 0; mi < 4; mi++) {
#pragma unroll
        for (int r = 0; r < 4; r++) {
          int i = m0 + wr * 64 + mi * 16 + fh * 4 + r;
          ((float*)outp)[(size_t)i * 1024 + j] = acc[mi][nj][r] + bj;
        }
      }
    }
    return;
  }

  // stage bf16 result into 128x128 LDS tile, XOR-swizzled (j ^= (i&7)<<3)
  float scale = (mode == 0) ? 0.125f : 1.0f;
#pragma unroll
  for (int nj = 0; nj < 4; nj++) {
    int j = wc * 64 + nj * 16 + fr;
    float bj = bias[n0 + j];
#pragma unroll
    for (int mi = 0; mi < 4; mi++) {
#pragma unroll
      for (int r = 0; r < 4; r++) {
        int i = wr * 64 + mi * 16 + fh * 4 + r;
        smem[i * 128 + (j ^ ((i & 7) << 3))] = f2bf((acc[mi][nj][r] + bj) * scale);
      }
    }
  }
  __syncthreads();

  if (mode == 2) {
    // fused transpose: vt[n][d][t], t-run of 16 per (b,h,d) -> 2 dwordx4
    int t0 = m0 >> 3;
#pragma unroll
    for (int rr2 = 0; rr2 < 4; ++rr2) {
      int rid = rr2 * 256 + tid;           // 0..1023
      int b = rid & 7, jh = (rid >> 3) & 1, d = rid >> 4;
      int j_loc = jh * 64 + d;
      u16 tmp[16];
#pragma unroll
      for (int tt = 0; tt < 16; ++tt) {
        int i_loc = tt * 8 + b;
        tmp[tt] = smem[i_loc * 128 + (j_loc ^ ((i_loc & 7) << 3))];
      }
      int n = b * 16 + ((n0 + j_loc) >> 6);
      int d_ = (n0 + j_loc) & 63;
      u16* dst = (u16*)outp + (size_t)n * 65536 + (size_t)d_ * 1024 + t0;
      *reinterpret_cast<uint4*>(dst)     = *reinterpret_cast<const uint4*>(&tmp[0]);
      *reinterpret_cast<uint4*>(dst + 8) = *reinterpret_cast<const uint4*>(&tmp[8]);
    }
  } else {
    // coalesced [n][t][d] store: 2048 chunks of 8 bf16 (128B runs)
#pragma unroll
    for (int it = 0; it < 8; ++it) {
      int g = w * 512 + it * 64 + lane;
      int i = g >> 4;
      int cg = (g & 15) * 8;
      uint4 v = *reinterpret_cast<const uint4*>(&smem[i * 128 + (cg ^ ((i & 7) << 3))]);
      int t = (m0 + i) >> 3, b = i & 7;
      int jg = n0 + cg;
      int h = jg >> 6, d = jg & 63;
      *reinterpret_cast<uint4*>(&((u16*)outp)[((size_t)((b * 16 + h) * 1024 + t)) * 64 + d]) = v;
    }
  }
}

__global__ __launch_bounds__(256) void k_gemm_qkv(
    const u16* __restrict__ xq, const u16* __restrict__ xk, const u16* __restrict__ xv,
    const u16* __restrict__ wq, const u16* __restrict__ wk, const u16* __restrict__ wv,
    const float* __restrict__ bq, const float* __restrict__ bk, const float* __restrict__ bv,
    u16* __restrict__ qo, u16* __restrict__ ko, u16* __restrict__ vto)
{
  int z = blockIdx.z;
  const u16* A = z == 0 ? xq : (z == 1 ? xk : xv);
  const u16* Bw = z == 0 ? wq : (z == 1 ? wk : wv);
  const float* bias = z == 0 ? bq : (z == 1 ? bk : bv);
  u16* o = z == 0 ? qo : (z == 1 ? ko : vto);
  gemm_core(A, Bw, bias, o, z);   // 0=q, 1=k, 2=v->vt
}

__global__ __launch_bounds__(256) void k_gemm_o(
    const u16* __restrict__ A, const u16* __restrict__ Bw,
    const float* __restrict__ bias, float* __restrict__ outp)
{
  gemm_core(A, Bw, bias, outp, 3);
}

// ---------------- flash attention step: one 64-s block for one t-block ----------------
__device__ __forceinline__ void attn_step(
    const u16* lds_k, u16* lds_p, const bf16x8 (&vf)[2][4],
    int sb, int tb_, int w, int fr, int fh,
    bf16x8 qf0, bf16x8 qf1,
    f32x4 (&oacc)[4], float (&m4)[4], float (&l4)[4])
{
  int t0 = tb_ * 64 + w * 16;
  f32x4 dd[4];
#pragma unroll
  for (int ss = 0; ss < 4; ++ss) {
    int row = ss * 16 + fr;
    const u16* kr = lds_k + row * 64;
    int c0 = (fh * 16) ^ ((row & 7) << 4);
    int c1 = (64 + fh * 16) ^ ((row & 7) << 4);
    bf16x8 kf0 = *reinterpret_cast<const bf16x8*>(kr + (c0 >> 1));
    bf16x8 kf1 = *reinterpret_cast<const bf16x8*>(kr + (c1 >> 1));
    f32x4 z = {0.f, 0.f, 0.f, 0.f};
    z = mfma16(qf0, kf0, z);
    dd[ss] = mfma16(qf1, kf1, z);
  }
  if (sb == tb_) {   // diagonal block: causal mask
#pragma unroll
    for (int ss = 0; ss < 4; ++ss) {
      int s_c = sb * 64 + ss * 16 + fr;
#pragma unroll
      for (int r = 0; r < 4; ++r)
        if (s_c > t0 + fh * 4 + r) dd[ss][r] = -3.0e38f;
    }
  }
  float mn[4], scale[4];
#pragma unroll
  for (int r = 0; r < 4; ++r) {
    float bm = fmaxf(fmaxf(dd[0][r], dd[1][r]), fmaxf(dd[2][r], dd[3][r]));
#pragma unroll
    for (int bmk = 1; bmk < 16; bmk <<= 1)
      bm = fmaxf(bm, __shfl_xor(bm, bmk, 64));
    mn[r] = fmaxf(m4[r], bm);
    scale[r] = __expf(m4[r] - mn[r]);
    m4[r] = mn[r];
  }
#pragma unroll
  for (int ss = 0; ss < 4; ++ss) {
#pragma unroll
    for (int r = 0; r < 4; ++r) {
      float p = __expf(dd[ss][r] - mn[r]);
      dd[ss][r] = p;
      int row = fh * 4 + r;
      int cb = ((ss * 16 + fr) * 2) ^ ((row & 7) << 4);
      lds_p[row * 64 + (cb >> 1)] = f2bf(p);
    }
  }
#pragma unroll
  for (int r = 0; r < 4; ++r) {
    float s = (dd[0][r] + dd[1][r]) + (dd[2][r] + dd[3][r]);
#pragma unroll
    for (int bmk = 1; bmk < 16; bmk <<= 1)
      s += __shfl_xor(s, bmk, 64);
    l4[r] = l4[r] * scale[r] + s;
#pragma unroll
    for (int db = 0; db < 4; ++db) oacc[db][r] *= scale[r];
  }
  asm volatile("s_waitcnt lgkmcnt(0)" ::: "memory");
  __builtin_amdgcn_sched_barrier(0);
#pragma unroll
  for (int ks = 0; ks < 2; ++ks) {
    int pc = (ks * 64 + fh * 16) ^ ((fr & 7) << 4);
    bf16x8 pa = *reinterpret_cast<const bf16x8*>(lds_p + fr * 64 + (pc >> 1));
#pragma unroll
    for (int db = 0; db < 4; ++db)
      oacc[db] = mfma16(pa, vf[ks][db], oacc[db]);
  }
}

// ---------------- attention: grid (n=128, j=8); block does t-blocks {15-j, j} ----------------
__global__ __launch_bounds__(256) void k_attn(
    const u16* __restrict__ qb, const u16* __restrict__ kb, const u16* __restrict__ vt,
    float* __restrict__ m_ws, float* __restrict__ l_ws, u16* __restrict__ attn_pre)
{
  __shared__ u16 kT[2][64 * 64];
  __shared__ u16 pT[4][16 * 64];
  int tid = threadIdx.x, w = tid >> 6, lane = tid & 63;
  int fr = lane & 15, fh = lane >> 4;
  int n = blockIdx.x, j = blockIdx.y;
  int tbH = 15 - j, tbL = j;
  const u16* kb_n = kb + (size_t)n * 1024 * 64;
  const u16* vt_n = vt + (size_t)n * 64 * 1024;

  bf16x8 qfH0, qfH1, qfL0, qfL1;
  {
    const u16* q = qb + ((size_t)n * 1024 + tbH * 64 + w * 16 + fr) * 64;
    qfH0 = *reinterpret_cast<const bf16x8*>(q + fh * 8);
    qfH1 = *reinterpret_cast<const bf16x8*>(q + 32 + fh * 8);
    q = qb + ((size_t)n * 1024 + tbL * 64 + w * 16 + fr) * 64;
    qfL0 = *reinterpret_cast<const bf16x8*>(q + fh * 8);
    qfL1 = *reinterpret_cast<const bf16x8*>(q + 32 + fh * 8);
  }
  f32x4 oaccH[4], oaccL[4];
  float mH[4], lH[4], mL[4], lL[4];
#pragma unroll
  for (int i = 0; i < 4; ++i) {
    oaccH[i] = (f32x4){0.f, 0.f, 0.f, 0.f};
    oaccL[i] = (f32x4){0.f, 0.f, 0.f, 0.f};
    mH[i] = -3.0e38f; lH[i] = 0.f; mL[i] = -3.0e38f; lL[i] = 0.f;
  }

  auto stage = [&](int buf, int sb) {
#pragma unroll
    for (int it = 0; it < 2; ++it) {
      int rbase = w * 16 + it * 8;
      int row = rbase + (lane >> 3);
      int colb = ((lane & 7) * 16) ^ ((lane >> 3) << 4);
      const u16* src = kb_n + ((size_t)(sb * 64 + row)) * 64 + (colb >> 1);
      gll16(src, &kT[buf][rbase * 64]);
    }
  };

  stage(0, 0);
  asm volatile("s_waitcnt vmcnt(0)" ::: "memory");
  __syncthreads();
  int cur = 0;
  for (int sb = 0; sb <= tbH; ++sb) {
    if (sb < tbH) stage(cur ^ 1, sb + 1);
    bf16x8 vf[2][4];
#pragma unroll
    for (int ks = 0; ks < 2; ++ks)
#pragma unroll
      for (int db = 0; db < 4; ++db)
        vf[ks][db] = *reinterpret_cast<const bf16x8*>(
            vt_n + ((size_t)(db * 16 + fr)) * 1024 + sb * 64 + ks * 32 + fh * 8);
    attn_step(kT[cur], pT[w], vf, sb, tbH, w, fr, fh, qfH0, qfH1, oaccH, mH, lH);
    if (sb <= tbL)
      attn_step(kT[cur], pT[w], vf, sb, tbL, w, fr, fh, qfL0, qfL1, oaccL, mL, lL);
    asm volatile("s_waitcnt vmcnt(0)" ::: "memory");
    __syncthreads();
    cur ^= 1;
  }

  int b_ = n >> 4, h_ = n & 15;
  {
    int t0 = tbH * 64 + w * 16;
    if (fr == 0) {
#pragma unroll
      for (int r = 0; r < 4; ++r) {
        m_ws[n * 1024 + t0 + fh * 4 + r] = mH[r];
        l_ws[n * 1024 + t0 + fh * 4 + r] = lH[r];
      }
    }
#pragma unroll
    for (int db = 0; db < 4; ++db)
#pragma unroll
      for (int r = 0; r < 4; ++r)
        attn_pre[((size_t)((t0 + fh * 4 + r) * 8 + b_)) * 1024 + h_ * 64 + db * 16 + fr] =
            f2bf(oaccH[db][r] / lH[r]);
  }
  {
    int t0 = tbL * 64 + w * 16;
    if (fr == 0) {
#pragma unroll
      for (int r = 0; r < 4; ++r) {
        m_ws[n * 1024 + t0 + fh * 4 + r] = mL[r];
        l_ws[n * 1024 + t0 + fh * 4 + r] = lL[r];
      }
    }
#pragma unroll
    for (int db = 0; db < 4; ++db)
#pragma unroll
      for (int r = 0; r < 4; ++r)
        attn_pre[((size_t)((t0 + fh * 4 + r) * 8 + b_)) * 1024 + h_ * 64 + db * 16 + fr] =
            f2bf(oaccL[db][r] / lL[r]);
  }
}

// ---------------- weights + avg: r16 dbuf structure, b-local XCD mapping ----------------
// grid = 256 x 512, 128 KB LDS. NEW: b = pid & 7, pr = pid >> 3  =>  XCD = pid%8 = b.
// All 32 same-b blocks co-resident on ONE XCD: K[b] (2 MB) + Q[b] (2 MB) fit the 4 MB
// XCD L2, so K is fetched from HBM once (16 MB total) instead of per-XCD streaming
// (up to 512 MB). Chunks/vmcnt identical to r13/r16.
__global__ __launch_bounds__(512) void k_weights(
    const u16* __restrict__ qb, const u16* __restrict__ kb,
    const float* __restrict__ m_ws, const float* __restrict__ l_ws,
    float* __restrict__ wout, float* __restrict__ avg)
{
  __shared__ u16 kT[2][512 * 64];   // 2 x 64 KB, swizzled
  const float L2E = 1.4426950408889634f;
  int pid = blockIdx.x;
  int b = pid & 7, pr = pid >> 3;   // XCD(pid%8) == b  -> K[b] L2-resident
  int tid = threadIdx.x;
  int w = tid >> 6, lane = tid & 63, fr = lane & 15, fh = lane >> 4;
  f32x4 zero4 = {0.f, 0.f, 0.f, 0.f};

  int pA = pr, pB = 63 - pr;       // pA < 32 <= pB
  int t0A = pA * 16, t0B = pB * 16;

  f32x4 avgA[8], avgB[8];
#pragma unroll
  for (int i = 0; i < 8; ++i) { avgA[i] = zero4; avgB[i] = zero4; }

  const int srow8 = lane >> 3;                        // 0..7
  const int scolb = ((lane & 7) * 16) ^ (srow8 << 4); // pre-swizzled byte col

  auto stage = [&](int buf, int cc) {
    const u16* kb_n = kb + (size_t)(b * 16 + (cc >> 1)) * 65536;
    int base = (cc & 1) * 512;
#pragma unroll
    for (int j = 0; j < 8; ++j) {
      int rbase = j * 64 + w * 8;
      const u16* src = kb_n + ((size_t)(base + rbase + srow8)) * 64 + (scolb >> 1);
      gll16(src, &kT[buf][rbase * 64]);
    }
  };

  stage(0, 0);
  int cur = 0;

  bf16x8 qA0, qA1, qB0, qB1;
  float cA = 0.f, cB = 0.f;
  float* wrowA = nullptr;
  float* wrowB = nullptr;

  for (int h = 0; h < 16; ++h) {
    int n = b * 16 + h;
#pragma unroll
    for (int kh = 0; kh < 2; ++kh) {
      int cc = h * 2 + kh;
      __builtin_amdgcn_s_barrier();                 // A: all waves done reading buf^1
      __builtin_amdgcn_sched_barrier(0);
      if (cc < 31) stage(cur ^ 1, cc + 1);
      __builtin_amdgcn_sched_barrier(0);
      if (kh == 0) {
        if (h == 0) { asm volatile("s_waitcnt vmcnt(8)" ::: "memory"); }
        else        { asm volatile("s_waitcnt vmcnt(16)" ::: "memory"); }
      } else {
        if (h == 15) { asm volatile("s_waitcnt vmcnt(16)" ::: "memory"); }
        else         { asm volatile("s_waitcnt vmcnt(24)" ::: "memory"); }
      }
      __builtin_amdgcn_s_barrier();                 // B: staged data visible
      __builtin_amdgcn_sched_barrier(0);

      if (kh == 0) {   // per-h operands: 8 VMEM loads inside the counted region
        const u16* qrA = qb + ((size_t)n * 1024 + t0A + fr) * 64;
        const u16* qrB = qb + ((size_t)n * 1024 + t0B + fr) * 64;
        qA0 = *reinterpret_cast<const bf16x8*>(qrA + fh * 8);
        qA1 = *reinterpret_cast<const bf16x8*>(qrA + 32 + fh * 8);
        qB0 = *reinterpret_cast<const bf16x8*>(qrB + fh * 8);
        qB1 = *reinterpret_cast<const bf16x8*>(qrB + 32 + fh * 8);
        cA = -m_ws[n * 1024 + t0A + fr] * L2E - __log2f(l_ws[n * 1024 + t0A + fr]);
        cB = -m_ws[n * 1024 + t0B + fr] * L2E - __log2f(l_ws[n * 1024 + t0B + fr]);
        wrowA = wout + ((size_t)n << 20) + ((size_t)t0A << 10);
        wrowB = wout + ((size_t)n << 20) + ((size_t)t0B << 10);
      }

      const u16* kbuf_l = kT[cur];
#pragma unroll
      for (int i = 0; i < 4; ++i) {
        int sl = w + 8 * i;                          // chunk-local s-block 0..31
        int sg = kh * 32 + sl;                       // global s-block 0..63
        f32x4 wvA = zero4, wvB = zero4;
        if (sg <= pB) {                              // wave-uniform
          int rowl = sl * 16 + fr;
          const u16* kr = &kbuf_l[rowl * 64];
          int c0 = (fh * 16) ^ ((rowl & 7) << 4);
          int c1 = (64 + fh * 16) ^ ((rowl & 7) << 4);
          bf16x8 kf0 = *reinterpret_cast<const bf16x8*>(kr + (c0 >> 1));
          bf16x8 kf1 = *reinterpret_cast<const bf16x8*>(kr + (c1 >> 1));
          if (sg <= pA) {                            // half A valid
            f32x4 dd = zero4;
            dd = mfma16(kf0, qA0, dd);
            dd = mfma16(kf1, qA1, dd);
#pragma unroll
            for (int rr = 0; rr < 4; ++rr) {
              bool valid = (sg < pA) | (fh * 4 + rr <= fr);
              wvA[rr] = valid ? __builtin_amdgcn_exp2f(dd[rr] * L2E + cA) : 0.f;
            }
          }
          {                                          // half B valid (sg <= pB)
            f32x4 dd = zero4;
            dd = mfma16(kf0, qB0, dd);
            dd = mfma16(kf1, qB1, dd);
#pragma unroll
            for (int rr = 0; rr < 4; ++rr) {
              bool valid = (sg < pB) | (fh * 4 + rr <= fr);
              wvB[rr] = valid ? __builtin_amdgcn_exp2f(dd[rr] * L2E + cB) : 0.f;
            }
          }
        }
        avgA[kh * 4 + i] += wvA;
        avgB[kh * 4 + i] += wvB;
        *reinterpret_cast<f32x4*>(wrowA + (size_t)fr * 1024 + sg * 16 + fh * 4) = wvA;
        *reinterpret_cast<f32x4*>(wrowB + (size_t)fr * 1024 + sg * 16 + fh * 4) = wvB;
      }
      cur ^= 1;
    }
  }

  // avg: rows t0..t0+15 for both panels; ALL s-slots written (invalid = zero regs)
  float* arowA = avg + (((size_t)b << 10) + t0A) * 1024;
  float* arowB = avg + (((size_t)b << 10) + t0B) * 1024;
#pragma unroll
  for (int i = 0; i < 8; ++i) {
    int sg = (i >> 2) * 32 + (w + 8 * (i & 3));
    f32x4 vA = avgA[i], vB = avgB[i];
#pragma unroll
    for (int rr = 0; rr < 4; ++rr) { vA[rr] *= 0.0625f; vB[rr] *= 0.0625f; }
    *reinterpret_cast<f32x4*>(arowA + (size_t)fr * 1024 + sg * 16 + fh * 4) = vA;
    *reinterpret_cast<f32x4*>(arowB + (size_t)fr * 1024 + sg * 16 + fh * 4) = vB;
  }
}

// ---------------- launcher ----------------
extern "C" void kernel_launch(void* const* d_in, const int* in_sizes, int n_in,
                              void* d_out, int out_size, void* d_ws, size_t ws_size,
                              hipStream_t stream)
{
  const float* query = (const float*)d_in[0];
  const float* key_  = (const float*)d_in[1];
  const float* value = (const float*)d_in[2];
  const float* Wq = (const float*)d_in[5];
  const float* bq = (const float*)d_in[6];
  const float* Wk = (const float*)d_in[7];
  const float* bk = (const float*)d_in[8];
  const float* Wv = (const float*)d_in[9];
  const float* bv = (const float*)d_in[10];
  const float* Wo = (const float*)d_in[11];
  const float* bo = (const float*)d_in[12];

  char* ws = (char*)d_ws;
  size_t off = 0;
  auto alloc = [&](size_t bytes) { char* p = ws + off; off += (bytes + 255) & ~255ull; return p; };

  u16* xq   = (u16*)alloc(8192ull * 1024 * 2);
  u16* xk   = (u16*)alloc(8192ull * 1024 * 2);
  u16* xv   = (u16*)alloc(8192ull * 1024 * 2);
  u16* wqb  = (u16*)alloc(1024ull * 1024 * 2);
  u16* wkb  = (u16*)alloc(1024ull * 1024 * 2);
  u16* wvb  = (u16*)alloc(1024ull * 1024 * 2);
  u16* wob  = (u16*)alloc(1024ull * 1024 * 2);
  u16* qbuf = (u16*)alloc(128ull * 1024 * 64 * 2);
  u16* kbuf = (u16*)alloc(128ull * 1024 * 64 * 2);
  u16* vtb  = (u16*)alloc(128ull * 64 * 1024 * 2);
  u16* apre = (u16*)alloc(8192ull * 1024 * 2);
  float* mws = (float*)alloc(128ull * 1024 * 4);
  float* lws = (float*)alloc(128ull * 1024 * 4);

  float* out_attn = (float*)d_out;                  // [1024,8,1024]
  float* out_avg  = out_attn + 8388608;             // [8,1024,1024]
  float* out_w    = out_avg + 8388608;              // [8,16,1024,1024]

  k_cvt_all<<<28672, 256, 0, stream>>>(query, key_, value, Wq, Wk, Wv, Wo,
                                       xq, xk, xv, wqb, wkb, wvb, wob);

  k_gemm_qkv<<<dim3(64, 8, 3), 256, 0, stream>>>(xq, xk, xv, wqb, wkb, wvb,
                                                 bq, bk, bv, qbuf, kbuf, vtb);

  k_attn<<<dim3(128, 8), 256, 0, stream>>>(qbuf, kbuf, vtb, mws, lws, apre);
  k_weights<<<256, 512, 0, stream>>>(qbuf, kbuf, mws, lws, out_w, out_avg);
  k_gemm_o<<<dim3(64, 8), 256, 0, stream>>>(apre, wob, bo, out_attn);
}

// Round 19
// 364.234 us; speedup vs baseline: 1.5563x; 1.0464x over previous
//
#include <hip/hip_runtime.h>
#include <hip/hip_bf16.h>
#include <stdint.h>

typedef unsigned short u16;
typedef __attribute__((ext_vector_type(8))) short bf16x8;
typedef __attribute__((ext_vector_type(4))) float f32x4;

#define LDS_AS __attribute__((address_space(3)))
#define GLB_AS __attribute__((address_space(1)))

// T=1024, B=8, E=1024, H=16, hd=64, N=B*H=128, M=T*B=8192

__device__ __forceinline__ u16 f2bf(float f) {
  union { float f; uint32_t u; } v; v.f = f;
  uint32_t u = v.u;
  u += 0x7FFFu + ((u >> 16) & 1u);   // RNE
  return (u16)(u >> 16);
}

__device__ __forceinline__ f32x4 mfma16(bf16x8 a, bf16x8 b, f32x4 c) {
  return __builtin_amdgcn_mfma_f32_16x16x32_bf16(a, b, c, 0, 0, 0);
}

__device__ __forceinline__ void gll16(const void* g, void* l) {
  __builtin_amdgcn_global_load_lds((const GLB_AS void*)(uintptr_t)g,
                                   (LDS_AS void*)(uintptr_t)l, 16, 0, 0);
}

// ---------------- fp32 -> bf16 convert, single launch for all 7 tensors ----------------
__global__ __launch_bounds__(256) void k_cvt_all(
    const float* __restrict__ a0, const float* __restrict__ a1, const float* __restrict__ a2,
    const float* __restrict__ w0, const float* __restrict__ w1,
    const float* __restrict__ w2, const float* __restrict__ w3,
    u16* __restrict__ da0, u16* __restrict__ da1, u16* __restrict__ da2,
    u16* __restrict__ dw0, u16* __restrict__ dw1, u16* __restrict__ dw2, u16* __restrict__ dw3)
{
  int gid = blockIdx.x;
  const float* s; u16* d; int idx;
  if (gid < 24576) {
    int seg = gid >> 13; idx = gid & 8191;
    s = seg == 0 ? a0 : (seg == 1 ? a1 : a2);
    d = seg == 0 ? da0 : (seg == 1 ? da1 : da2);
  } else {
    int g2 = gid - 24576;
    int seg = g2 >> 10; idx = g2 & 1023;
    s = seg == 0 ? w0 : (seg == 1 ? w1 : (seg == 2 ? w2 : w3));
    d = seg == 0 ? dw0 : (seg == 1 ? dw1 : (seg == 2 ? dw2 : dw3));
  }
  int i = (idx * 256 + threadIdx.x) * 4;
  float4 v = *reinterpret_cast<const float4*>(s + i);
  ushort4 o;
  o.x = f2bf(v.x); o.y = f2bf(v.y); o.z = f2bf(v.z); o.w = f2bf(v.w);
  *reinterpret_cast<ushort4*>(d + i) = o;
}

// ---------------- GEMM core ----------------
// mode 0: *0.125 bf16 -> [n][t][d] (q) ; mode 1: bf16 -> [n][t][d] (k)
// mode 2: bf16 -> vt[n][d][t] (v, fused transpose) ; mode 3: fp32 -> [i][j]
__device__ __forceinline__ void gemm_core(
    const u16* __restrict__ A, const u16* __restrict__ Bw,
    const float* __restrict__ bias, void* __restrict__ outp, int mode)
{
  __shared__ u16 smem[2 * 128 * 64];   // staging A/B; epilogue: 128x128 bf16 tile
  u16* aLds = smem;
  u16* bLds = smem + 128 * 64;
  const int tid = threadIdx.x;
  const int w = tid >> 6, lane = tid & 63;
  const int fr = lane & 15, fh = lane >> 4;
  const int m0 = blockIdx.x * 128, n0 = blockIdx.y * 128;
  const int wr = w >> 1, wc = w & 1;
  const int srow = tid >> 3, scol = (tid & 7) * 8;

  f32x4 zero4 = {0.f, 0.f, 0.f, 0.f};
  f32x4 acc[4][4];
#pragma unroll
  for (int i = 0; i < 4; i++)
#pragma unroll
    for (int j = 0; j < 4; j++) acc[i][j] = zero4;

  const u16* ag = A + (size_t)(m0 + srow) * 1024 + scol;
  const u16* bg = Bw + (size_t)(n0 + srow) * 1024 + scol;

  for (int k0 = 0; k0 < 1024; k0 += 64) {
#pragma unroll
    for (int it = 0; it < 4; ++it) {
      gll16(ag + (size_t)it * 32 * 1024 + k0, aLds + it * 2048 + w * 512);
      gll16(bg + (size_t)it * 32 * 1024 + k0, bLds + it * 2048 + w * 512);
    }
    __syncthreads();
#pragma unroll
    for (int ks = 0; ks < 2; ++ks) {
      bf16x8 af[4], bfr[4];
#pragma unroll
      for (int mi = 0; mi < 4; mi++)
        af[mi] = *reinterpret_cast<const bf16x8*>(&aLds[(wr * 64 + mi * 16 + fr) * 64 + ks * 32 + fh * 8]);
#pragma unroll
      for (int nj = 0; nj < 4; nj++)
        bfr[nj] = *reinterpret_cast<const bf16x8*>(&bLds[(wc * 64 + nj * 16 + fr) * 64 + ks * 32 + fh * 8]);
#pragma unroll
      for (int mi = 0; mi < 4; mi++)
#pragma unroll
        for (int nj = 0; nj < 4; nj++)
          acc[mi][nj] = mfma16(af[mi], bfr[nj], acc[mi][nj]);
    }
    __syncthreads();
  }

  if (mode == 3) {
#pragma unroll
    for (int nj = 0; nj < 4; nj++) {
      int j = n0 + wc * 64 + nj * 16 + fr;
      float bj = bias[j];
#pragma unroll
      for (int mi = 0; mi < 4; mi++) {
#pragma unroll
        for (int r = 0; r < 4; r++) {
          int i = m0 + wr * 64 + mi * 16 + fh * 4 + r;
          ((float*)outp)[(size_t)i * 1024 + j] = acc[mi][nj][r] + bj;
        }
      }
    }
    return;
  }

  // stage bf16 result into 128x128 LDS tile, XOR-swizzled (j ^= (i&7)<<3)
  float scale = (mode == 0) ? 0.125f : 1.0f;
#pragma unroll
  for (int nj = 0; nj < 4; nj++) {
    int j = wc * 64 + nj * 16 + fr;
    float bj = bias[n0 + j];
#pragma unroll
    for (int mi = 0; mi < 4; mi++) {
#pragma unroll
      for (int r = 0; r < 4; r++) {
        int i = wr * 64 + mi * 16 + fh * 4 + r;
        smem[i * 128 + (j ^ ((i & 7) << 3))] = f2bf((acc[mi][nj][r] + bj) * scale);
      }
    }
  }
  __syncthreads();

  if (mode == 2) {
    // fused transpose: vt[n][d][t], t-run of 16 per (b,h,d) -> 2 dwordx4
    int t0 = m0 >> 3;
#pragma unroll
    for (int rr2 = 0; rr2 < 4; ++rr2) {
      int rid = rr2 * 256 + tid;           // 0..1023
      int b = rid & 7, jh = (rid >> 3) & 1, d = rid >> 4;
      int j_loc = jh * 64 + d;
      u16 tmp[16];
#pragma unroll
      for (int tt = 0; tt < 16; ++tt) {
        int i_loc = tt * 8 + b;
        tmp[tt] = smem[i_loc * 128 + (j_loc ^ ((i_loc & 7) << 3))];
      }
      int n = b * 16 + ((n0 + j_loc) >> 6);
      int d_ = (n0 + j_loc) & 63;
      u16* dst = (u16*)outp + (size_t)n * 65536 + (size_t)d_ * 1024 + t0;
      *reinterpret_cast<uint4*>(dst)     = *reinterpret_cast<const uint4*>(&tmp[0]);
      *reinterpret_cast<uint4*>(dst + 8) = *reinterpret_cast<const uint4*>(&tmp[8]);
    }
  } else {
    // coalesced [n][t][d] store: 2048 chunks of 8 bf16 (128B runs)
#pragma unroll
    for (int it = 0; it < 8; ++it) {
      int g = w * 512 + it * 64 + lane;
      int i = g >> 4;
      int cg = (g & 15) * 8;
      uint4 v = *reinterpret_cast<const uint4*>(&smem[i * 128 + (cg ^ ((i & 7) << 3))]);
      int t = (m0 + i) >> 3, b = i & 7;
      int jg = n0 + cg;
      int h = jg >> 6, d = jg & 63;
      *reinterpret_cast<uint4*>(&((u16*)outp)[((size_t)((b * 16 + h) * 1024 + t)) * 64 + d]) = v;
    }
  }
}

__global__ __launch_bounds__(256) void k_gemm_qkv(
    const u16* __restrict__ xq, const u16* __restrict__ xk, const u16* __restrict__ xv,
    const u16* __restrict__ wq, const u16* __restrict__ wk, const u16* __restrict__ wv,
    const float* __restrict__ bq, const float* __restrict__ bk, const float* __restrict__ bv,
    u16* __restrict__ qo, u16* __restrict__ ko, u16* __restrict__ vto)
{
  int z = blockIdx.z;
  const u16* A = z == 0 ? xq : (z == 1 ? xk : xv);
  const u16* Bw = z == 0 ? wq : (z == 1 ? wk : wv);
  const float* bias = z == 0 ? bq : (z == 1 ? bk : bv);
  u16* o = z == 0 ? qo : (z == 1 ? ko : vto);
  gemm_core(A, Bw, bias, o, z);   // 0=q, 1=k, 2=v->vt
}

__global__ __launch_bounds__(256) void k_gemm_o(
    const u16* __restrict__ A, const u16* __restrict__ Bw,
    const float* __restrict__ bias, float* __restrict__ outp)
{
  gemm_core(A, Bw, bias, outp, 3);
}

// ---------------- flash attention step: one 64-s block for one t-block ----------------
__device__ __forceinline__ void attn_step(
    const u16* lds_k, u16* lds_p, const bf16x8 (&vf)[2][4],
    int sb, int tb_, int w, int fr, int fh,
    bf16x8 qf0, bf16x8 qf1,
    f32x4 (&oacc)[4], float (&m4)[4], float (&l4)[4])
{
  int t0 = tb_ * 64 + w * 16;
  f32x4 dd[4];
#pragma unroll
  for (int ss = 0; ss < 4; ++ss) {
    int row = ss * 16 + fr;
    const u16* kr = lds_k + row * 64;
    int c0 = (fh * 16) ^ ((row & 7) << 4);
    int c1 = (64 + fh * 16) ^ ((row & 7) << 4);
    bf16x8 kf0 = *reinterpret_cast<const bf16x8*>(kr + (c0 >> 1));
    bf16x8 kf1 = *reinterpret_cast<const bf16x8*>(kr + (c1 >> 1));
    f32x4 z = {0.f, 0.f, 0.f, 0.f};
    z = mfma16(qf0, kf0, z);
    dd[ss] = mfma16(qf1, kf1, z);
  }
  if (sb == tb_) {   // diagonal block: causal mask
#pragma unroll
    for (int ss = 0; ss < 4; ++ss) {
      int s_c = sb * 64 + ss * 16 + fr;
#pragma unroll
      for (int r = 0; r < 4; ++r)
        if (s_c > t0 + fh * 4 + r) dd[ss][r] = -3.0e38f;
    }
  }
  float mn[4], scale[4];
#pragma unroll
  for (int r = 0; r < 4; ++r) {
    float bm = fmaxf(fmaxf(dd[0][r], dd[1][r]), fmaxf(dd[2][r], dd[3][r]));
#pragma unroll
    for (int bmk = 1; bmk < 16; bmk <<= 1)
      bm = fmaxf(bm, __shfl_xor(bm, bmk, 64));
    mn[r] = fmaxf(m4[r], bm);
    scale[r] = __expf(m4[r] - mn[r]);
    m4[r] = mn[r];
  }
#pragma unroll
  for (int ss = 0; ss < 4; ++ss) {
#pragma unroll
    for (int r = 0; r < 4; ++r) {
      float p = __expf(dd[ss][r] - mn[r]);
      dd[ss][r] = p;
      int row = fh * 4 + r;
      int cb = ((ss * 16 + fr) * 2) ^ ((row & 7) << 4);
      lds_p[row * 64 + (cb >> 1)] = f2bf(p);
    }
  }
#pragma unroll
  for (int r = 0; r < 4; ++r) {
    float s = (dd[0][r] + dd[1][r]) + (dd[2][r] + dd[3][r]);
#pragma unroll
    for (int bmk = 1; bmk < 16; bmk <<= 1)
      s += __shfl_xor(s, bmk, 64);
    l4[r] = l4[r] * scale[r] + s;
#pragma unroll
    for (int db = 0; db < 4; ++db) oacc[db][r] *= scale[r];
  }
  asm volatile("s_waitcnt lgkmcnt(0)" ::: "memory");
  __builtin_amdgcn_sched_barrier(0);
#pragma unroll
  for (int ks = 0; ks < 2; ++ks) {
    int pc = (ks * 64 + fh * 16) ^ ((fr & 7) << 4);
    bf16x8 pa = *reinterpret_cast<const bf16x8*>(lds_p + fr * 64 + (pc >> 1));
#pragma unroll
    for (int db = 0; db < 4; ++db)
      oacc[db] = mfma16(pa, vf[ks][db], oacc[db]);
  }
}

// ---------------- attention: grid (n=128, j=8); block does t-blocks {15-j, j} ----------------
__global__ __launch_bounds__(256) void k_attn(
    const u16* __restrict__ qb, const u16* __restrict__ kb, const u16* __restrict__ vt,
    float* __restrict__ m_ws, float* __restrict__ l_ws, u16* __restrict__ attn_pre)
{
  __shared__ u16 kT[2][64 * 64];
  __shared__ u16 pT[4][16 * 64];
  int tid = threadIdx.x, w = tid >> 6, lane = tid & 63;
  int fr = lane & 15, fh = lane >> 4;
  int n = blockIdx.x, j = blockIdx.y;
  int tbH = 15 - j, tbL = j;
  const u16* kb_n = kb + (size_t)n * 1024 * 64;
  const u16* vt_n = vt + (size_t)n * 64 * 1024;

  bf16x8 qfH0, qfH1, qfL0, qfL1;
  {
    const u16* q = qb + ((size_t)n * 1024 + tbH * 64 + w * 16 + fr) * 64;
    qfH0 = *reinterpret_cast<const bf16x8*>(q + fh * 8);
    qfH1 = *reinterpret_cast<const bf16x8*>(q + 32 + fh * 8);
    q = qb + ((size_t)n * 1024 + tbL * 64 + w * 16 + fr) * 64;
    qfL0 = *reinterpret_cast<const bf16x8*>(q + fh * 8);
    qfL1 = *reinterpret_cast<const bf16x8*>(q + 32 + fh * 8);
  }
  f32x4 oaccH[4], oaccL[4];
  float mH[4], lH[4], mL[4], lL[4];
#pragma unroll
  for (int i = 0; i < 4; ++i) {
    oaccH[i] = (f32x4){0.f, 0.f, 0.f, 0.f};
    oaccL[i] = (f32x4){0.f, 0.f, 0.f, 0.f};
    mH[i] = -3.0e38f; lH[i] = 0.f; mL[i] = -3.0e38f; lL[i] = 0.f;
  }

  auto stage = [&](int buf, int sb) {
#pragma unroll
    for (int it = 0; it < 2; ++it) {
      int rbase = w * 16 + it * 8;
      int row = rbase + (lane >> 3);
      int colb = ((lane & 7) * 16) ^ ((lane >> 3) << 4);
      const u16* src = kb_n + ((size_t)(sb * 64 + row)) * 64 + (colb >> 1);
      gll16(src, &kT[buf][rbase * 64]);
    }
  };

  stage(0, 0);
  asm volatile("s_waitcnt vmcnt(0)" ::: "memory");
  __syncthreads();
  int cur = 0;
  for (int sb = 0; sb <= tbH; ++sb) {
    if (sb < tbH) stage(cur ^ 1, sb + 1);
    bf16x8 vf[2][4];
#pragma unroll
    for (int ks = 0; ks < 2; ++ks)
#pragma unroll
      for (int db = 0; db < 4; ++db)
        vf[ks][db] = *reinterpret_cast<const bf16x8*>(
            vt_n + ((size_t)(db * 16 + fr)) * 1024 + sb * 64 + ks * 32 + fh * 8);
    attn_step(kT[cur], pT[w], vf, sb, tbH, w, fr, fh, qfH0, qfH1, oaccH, mH, lH);
    if (sb <= tbL)
      attn_step(kT[cur], pT[w], vf, sb, tbL, w, fr, fh, qfL0, qfL1, oaccL, mL, lL);
    asm volatile("s_waitcnt vmcnt(0)" ::: "memory");
    __syncthreads();
    cur ^= 1;
  }

  int b_ = n >> 4, h_ = n & 15;
  {
    int t0 = tbH * 64 + w * 16;
    if (fr == 0) {
#pragma unroll
      for (int r = 0; r < 4; ++r) {
        m_ws[n * 1024 + t0 + fh * 4 + r] = mH[r];
        l_ws[n * 1024 + t0 + fh * 4 + r] = lH[r];
      }
    }
#pragma unroll
    for (int db = 0; db < 4; ++db)
#pragma unroll
      for (int r = 0; r < 4; ++r)
        attn_pre[((size_t)((t0 + fh * 4 + r) * 8 + b_)) * 1024 + h_ * 64 + db * 16 + fr] =
            f2bf(oaccH[db][r] / lH[r]);
  }
  {
    int t0 = tbL * 64 + w * 16;
    if (fr == 0) {
#pragma unroll
      for (int r = 0; r < 4; ++r) {
        m_ws[n * 1024 + t0 + fh * 4 + r] = mL[r];
        l_ws[n * 1024 + t0 + fh * 4 + r] = lL[r];
      }
    }
#pragma unroll
    for (int db = 0; db < 4; ++db)
#pragma unroll
      for (int r = 0; r < 4; ++r)
        attn_pre[((size_t)((t0 + fh * 4 + r) * 8 + b_)) * 1024 + h_ * 64 + db * 16 + fr] =
            f2bf(oaccL[db][r] / lL[r]);
  }
}

// ---------------- weights + avg: r18 + NONTEMPORAL stores ----------------
// b-local XCD mapping (b = pid&7 => all 32 same-b blocks on one XCD; K[b]+Q[b] = 4MB
// fit its L2) + nt stores so the 512MB wout stream does NOT evict K/Q from that L2.
// Store count/order unchanged from r13/r16/r18 => counted-vmcnt accounting still exact.
__global__ __launch_bounds__(512) void k_weights(
    const u16* __restrict__ qb, const u16* __restrict__ kb,
    const float* __restrict__ m_ws, const float* __restrict__ l_ws,
    float* __restrict__ wout, float* __restrict__ avg)
{
  __shared__ u16 kT[2][512 * 64];   // 2 x 64 KB, swizzled
  const float L2E = 1.4426950408889634f;
  int pid = blockIdx.x;
  int b = pid & 7, pr = pid >> 3;   // XCD(pid%8) == b  -> K[b] L2-resident
  int tid = threadIdx.x;
  int w = tid >> 6, lane = tid & 63, fr = lane & 15, fh = lane >> 4;
  f32x4 zero4 = {0.f, 0.f, 0.f, 0.f};

  int pA = pr, pB = 63 - pr;       // pA < 32 <= pB
  int t0A = pA * 16, t0B = pB * 16;

  f32x4 avgA[8], avgB[8];
#pragma unroll
  for (int i = 0; i < 8; ++i) { avgA[i] = zero4; avgB[i] = zero4; }

  const int srow8 = lane >> 3;                        // 0..7
  const int scolb = ((lane & 7) * 16) ^ (srow8 << 4); // pre-swizzled byte col

  auto stage = [&](int buf, int cc) {
    const u16* kb_n = kb + (size_t)(b * 16 + (cc >> 1)) * 65536;
    int base = (cc & 1) * 512;
#pragma unroll
    for (int j = 0; j < 8; ++j) {
      int rbase = j * 64 + w * 8;
      const u16* src = kb_n + ((size_t)(base + rbase + srow8)) * 64 + (scolb >> 1);
      gll16(src, &kT[buf][rbase * 64]);
    }
  };

  stage(0, 0);
  int cur = 0;

  bf16x8 qA0, qA1, qB0, qB1;
  float cA = 0.f, cB = 0.f;
  float* wrowA = nullptr;
  float* wrowB = nullptr;

  for (int h = 0; h < 16; ++h) {
    int n = b * 16 + h;
#pragma unroll
    for (int kh = 0; kh < 2; ++kh) {
      int cc = h * 2 + kh;
      __builtin_amdgcn_s_barrier();                 // A: all waves done reading buf^1
      __builtin_amdgcn_sched_barrier(0);
      if (cc < 31) stage(cur ^ 1, cc + 1);
      __builtin_amdgcn_sched_barrier(0);
      if (kh == 0) {
        if (h == 0) { asm volatile("s_waitcnt vmcnt(8)" ::: "memory"); }
        else        { asm volatile("s_waitcnt vmcnt(16)" ::: "memory"); }
      } else {
        if (h == 15) { asm volatile("s_waitcnt vmcnt(16)" ::: "memory"); }
        else         { asm volatile("s_waitcnt vmcnt(24)" ::: "memory"); }
      }
      __builtin_amdgcn_s_barrier();                 // B: staged data visible
      __builtin_amdgcn_sched_barrier(0);

      if (kh == 0) {   // per-h operands: 8 VMEM loads inside the counted region
        const u16* qrA = qb + ((size_t)n * 1024 + t0A + fr) * 64;
        const u16* qrB = qb + ((size_t)n * 1024 + t0B + fr) * 64;
        qA0 = *reinterpret_cast<const bf16x8*>(qrA + fh * 8);
        qA1 = *reinterpret_cast<const bf16x8*>(qrA + 32 + fh * 8);
        qB0 = *reinterpret_cast<const bf16x8*>(qrB + fh * 8);
        qB1 = *reinterpret_cast<const bf16x8*>(qrB + 32 + fh * 8);
        cA = -m_ws[n * 1024 + t0A + fr] * L2E - __log2f(l_ws[n * 1024 + t0A + fr]);
        cB = -m_ws[n * 1024 + t0B + fr] * L2E - __log2f(l_ws[n * 1024 + t0B + fr]);
        wrowA = wout + ((size_t)n << 20) + ((size_t)t0A << 10);
        wrowB = wout + ((size_t)n << 20) + ((size_t)t0B << 10);
      }

      const u16* kbuf_l = kT[cur];
#pragma unroll
      for (int i = 0; i < 4; ++i) {
        int sl = w + 8 * i;                          // chunk-local s-block 0..31
        int sg = kh * 32 + sl;                       // global s-block 0..63
        f32x4 wvA = zero4, wvB = zero4;
        if (sg <= pB) {                              // wave-uniform
          int rowl = sl * 16 + fr;
          const u16* kr = &kbuf_l[rowl * 64];
          int c0 = (fh * 16) ^ ((rowl & 7) << 4);
          int c1 = (64 + fh * 16) ^ ((rowl & 7) << 4);
          bf16x8 kf0 = *reinterpret_cast<const bf16x8*>(kr + (c0 >> 1));
          bf16x8 kf1 = *reinterpret_cast<const bf16x8*>(kr + (c1 >> 1));
          if (sg <= pA) {                            // half A valid
            f32x4 dd = zero4;
            dd = mfma16(kf0, qA0, dd);
            dd = mfma16(kf1, qA1, dd);
#pragma unroll
            for (int rr = 0; rr < 4; ++rr) {
              bool valid = (sg < pA) | (fh * 4 + rr <= fr);
              wvA[rr] = valid ? __builtin_amdgcn_exp2f(dd[rr] * L2E + cA) : 0.f;
            }
          }
          {                                          // half B valid (sg <= pB)
            f32x4 dd = zero4;
            dd = mfma16(kf0, qB0, dd);
            dd = mfma16(kf1, qB1, dd);
#pragma unroll
            for (int rr = 0; rr < 4; ++rr) {
              bool valid = (sg < pB) | (fh * 4 + rr <= fr);
              wvB[rr] = valid ? __builtin_amdgcn_exp2f(dd[rr] * L2E + cB) : 0.f;
            }
          }
        }
        avgA[kh * 4 + i] += wvA;
        avgB[kh * 4 + i] += wvB;
        __builtin_nontemporal_store(wvA,
            reinterpret_cast<f32x4*>(wrowA + (size_t)fr * 1024 + sg * 16 + fh * 4));
        __builtin_nontemporal_store(wvB,
            reinterpret_cast<f32x4*>(wrowB + (size_t)fr * 1024 + sg * 16 + fh * 4));
      }
      cur ^= 1;
    }
  }

  // avg: rows t0..t0+15 for both panels; ALL s-slots written (invalid = zero regs)
  float* arowA = avg + (((size_t)b << 10) + t0A) * 1024;
  float* arowB = avg + (((size_t)b << 10) + t0B) * 1024;
#pragma unroll
  for (int i = 0; i < 8; ++i) {
    int sg = (i >> 2) * 32 + (w + 8 * (i & 3));
    f32x4 vA = avgA[i], vB = avgB[i];
#pragma unroll
    for (int rr = 0; rr < 4; ++rr) { vA[rr] *= 0.0625f; vB[rr] *= 0.0625f; }
    __builtin_nontemporal_store(vA,
        reinterpret_cast<f32x4*>(arowA + (size_t)fr * 1024 + sg * 16 + fh * 4));
    __builtin_nontemporal_store(vB,
        reinterpret_cast<f32x4*>(arowB + (size_t)fr * 1024 + sg * 16 + fh * 4));
  }
}

// ---------------- launcher ----------------
extern "C" void kernel_launch(void* const* d_in, const int* in_sizes, int n_in,
                              void* d_out, int out_size, void* d_ws, size_t ws_size,
                              hipStream_t stream)
{
  const float* query = (const float*)d_in[0];
  const float* key_  = (const float*)d_in[1];
  const float* value = (const float*)d_in[2];
  const float* Wq = (const float*)d_in[5];
  const float* bq = (const float*)d_in[6];
  const float* Wk = (const float*)d_in[7];
  const float* bk = (const float*)d_in[8];
  const float* Wv = (const float*)d_in[9];
  const float* bv = (const float*)d_in[10];
  const float* Wo = (const float*)d_in[11];
  const float* bo = (const float*)d_in[12];

  char* ws = (char*)d_ws;
  size_t off = 0;
  auto alloc = [&](size_t bytes) { char* p = ws + off; off += (bytes + 255) & ~255ull; return p; };

  u16* xq   = (u16*)alloc(8192ull * 1024 * 2);
  u16* xk   = (u16*)alloc(8192ull * 1024 * 2);
  u16* xv   = (u16*)alloc(8192ull * 1024 * 2);
  u16* wqb  = (u16*)alloc(1024ull * 1024 * 2);
  u16* wkb  = (u16*)alloc(1024ull * 1024 * 2);
  u16* wvb  = (u16*)alloc(1024ull * 1024 * 2);
  u16* wob  = (u16*)alloc(1024ull * 1024 * 2);
  u16* qbuf = (u16*)alloc(128ull * 1024 * 64 * 2);
  u16* kbuf = (u16*)alloc(128ull * 1024 * 64 * 2);
  u16* vtb  = (u16*)alloc(128ull * 64 * 1024 * 2);
  u16* apre = (u16*)alloc(8192ull * 1024 * 2);
  float* mws = (float*)alloc(128ull * 1024 * 4);
  float* lws = (float*)alloc(128ull * 1024 * 4);

  float* out_attn = (float*)d_out;                  // [1024,8,1024]
  float* out_avg  = out_attn + 8388608;             // [8,1024,1024]
  float* out_w    = out_avg + 8388608;              // [8,16,1024,1024]

  k_cvt_all<<<28672, 256, 0, stream>>>(query, key_, value, Wq, Wk, Wv, Wo,
                                       xq, xk, xv, wqb, wkb, wvb, wob);

  k_gemm_qkv<<<dim3(64, 8, 3), 256, 0, stream>>>(xq, xk, xv, wqb, wkb, wvb,
                                                 bq, bk, bv, qbuf, kbuf, vtb);

  k_attn<<<dim3(128, 8), 256, 0, stream>>>(qbuf, kbuf, vtb, mws, lws, apre);
  k_weights<<<256, 512, 0, stream>>>(qbuf, kbuf, mws, lws, out_w, out_avg);
  k_gemm_o<<<dim3(64, 8), 256, 0, stream>>>(apre, wob, bo, out_attn);
}